// Round 15
// baseline (3523.258 us; speedup 1.0000x reference)
//
#include <hip/hip_runtime.h>
#include <stdint.h>

#define BATCH   4
#define NPTS    16384
#define NPOINT  1024
#define KNN     20
#define KSEL    21   // K+1, includes self

typedef unsigned long long u64;

// ---------------------------------------------------------------------------
// FUSED kernel, round 15: FPS blocks are now SINGLE-WAVE (no LDS, no
// barriers). r14 showed fusion works but fps is pinned at ~2.6us/iter; the
// removable part is the intra-block overhead (2 barriers + LDS reduce +
// LDS broadcast per iteration). 32 waves per batch, PPT=8 (32 data floats,
// fits the ~90-VGPR allocator grant, no spill). Per iter: 6-shuffle wave
// argmax -> lane0 publishes slot -> all lanes poll the 32-slot row (256B,
// one coalesced load) -> 6-shuffle reduce over lane-duplicated partials
// (duplicates are no-ops for (max val, min idx)) -> shfl broadcast ->
// uniform coords load. Slot protocol/tags/poison/replay semantics identical
// to validated r13/r14. FPS_STEP expression text unchanged -> bit-identical
// selections.
// ---------------------------------------------------------------------------
#define FPS_SUBS   32                    // single-wave fps blocks per batch
#define FPS_TPB    256                   // launch block size (both roles)
#define FPS_BLOCKS (BATCH * FPS_SUBS)    // 128
#define FPS_GT     (FPS_SUBS * 64)       // 2048 fps lanes per batch
#define FPS_PPT    (NPTS / FPS_GT)       // 8 points per lane
#define KNN_BLOCKS (BATCH * NPOINT / 4)  // 1024 (4 waves/block)

#define REPEAT8(M) M(0) M(1) M(2) M(3) M(4) M(5) M(6) M(7)

#define FPS_DECL(i) float px##i, py##i, pz##i, md##i;

#define FPS_INIT(i) { \
    int idx = (i) * FPS_GT + g; \
    px##i = P[idx * 3 + 0]; \
    py##i = P[idx * 3 + 1]; \
    pz##i = P[idx * 3 + 2]; \
    md##i = 1e10f; }

#define FPS_STEP(i) { \
    float dx = __fsub_rn(px##i, qx); \
    float dy = __fsub_rn(py##i, qy); \
    float dz = __fsub_rn(pz##i, qz); \
    float d  = __fadd_rn(__fadd_rn(__fmul_rn(dx, dx), __fmul_rn(dy, dy)), \
                         __fmul_rn(dz, dz)); \
    float m = fminf(md##i, d); \
    md##i = m; \
    bool g2 = (m > best); \
    best = g2 ? m : best; \
    bi   = g2 ? (i) : bi; }

__global__ __launch_bounds__(FPS_TPB)
void fused_kernel(const float* __restrict__ pts, float* __restrict__ out,
                  int* __restrict__ ws_ind, float* __restrict__ ws_query,
                  u64* __restrict__ slots,
                  float* __restrict__ out_nbr_mid,
                  float* __restrict__ out_d_mid) {
  if (blockIdx.x < FPS_BLOCKS) {
    // ---------------- FPS role: single wave, no LDS, no barriers ----------
    if (threadIdx.x >= 64) return;       // waves 1-3 retire immediately
    const int blk  = blockIdx.x;
    const int b    = blk >> 5;           // batch
    const int sub  = blk & 31;           // wave index within batch
    const int lane = threadIdx.x;
    const int g    = sub * 64 + lane;    // 0..2047 within batch
    const float* P = pts + (size_t)b * NPTS * 3;
    float* out_ind = out;
    float* out_q   = out + BATCH * NPOINT;

    REPEAT8(FPS_DECL)
    REPEAT8(FPS_INIT)

    if (sub == 0 && lane == 0) {
      out_ind[b * NPOINT] = 0.0f;
      ws_ind[b * NPOINT]  = 0;
      float ax = P[0], ay = P[1], az = P[2];
      size_t o0 = (size_t)(b * NPOINT) * 3;
      out_q[o0 + 0] = ax; out_q[o0 + 1] = ay; out_q[o0 + 2] = az;
      ws_query[o0 + 0] = ax; ws_query[o0 + 1] = ay; ws_query[o0 + 2] = az;
    }
    float qx = P[0], qy = P[1], qz = P[2];

    for (int it = 1; it < NPOINT; ++it) {
      float best = -1.0f;
      int bi = 0;
      REPEAT8(FPS_STEP)
      int bidx = bi * FPS_GT + g;

      // wave argmax -> lane 0, tie -> lower global index
#pragma unroll
      for (int off = 32; off >= 1; off >>= 1) {
        float ov = __shfl_down(best, off);
        int   oi = __shfl_down(bidx, off);
        if (ov > best || (ov == best && oi < bidx)) { best = ov; bidx = oi; }
      }

      u64* row = slots + (size_t)it * (BATCH * FPS_SUBS) + b * FPS_SUBS;
      if (lane == 0) {
        // publish: [63:32]=md bits (sign=0), [29:20]=it tag, [13:0]=idx
        u64 pv = ((u64)__float_as_uint(best) << 32) |
                 (unsigned)(bidx | (it << 20));
        __hip_atomic_store(&row[sub], pv, __ATOMIC_RELAXED,
                           __HIP_MEMORY_SCOPE_AGENT);
      }
      // all lanes poll (lanes 32-63 duplicate lanes 0-31 -> harmless)
      int j = lane & 31;
      u64 v;
      do {
        v = __hip_atomic_load(&row[j], __ATOMIC_RELAXED,
                              __HIP_MEMORY_SCOPE_AGENT);
      } while ((v >> 63) != 0 ||
               (((unsigned)(v >> 20)) & 0x3FFu) != (unsigned)it);
      float fv = __uint_as_float((unsigned)(v >> 32));
      int   fi = (int)((unsigned)v & 0xFFFFFu);
      // 6-step argmax over duplicated partials (exact for max/min-idx)
#pragma unroll
      for (int off = 32; off >= 1; off >>= 1) {
        float ofv = __shfl_down(fv, off);
        int   ofi = __shfl_down(fi, off);
        if (ofv > fv || (ofv == fv && ofi < fi)) { fv = ofv; fi = ofi; }
      }
      const int widx = __shfl(fi, 0);

      qx = P[widx * 3 + 0];
      qy = P[widx * 3 + 1];
      qz = P[widx * 3 + 2];

      if (sub == 0 && lane == 0) {
        out_ind[b * NPOINT + it] = (float)widx;
        ws_ind[b * NPOINT + it]  = widx;
        size_t o = (size_t)(b * NPOINT + it) * 3;
        out_q[o + 0] = qx; out_q[o + 1] = qy; out_q[o + 2] = qz;
        ws_query[o + 0] = qx; ws_query[o + 1] = qy; ws_query[o + 2] = qz;
      }
    }
  } else {
    // ---------------- knn_mid role: one wave per query (r14, validated) ---
#pragma clang fp contract(off)
    const int wv   = (blockIdx.x - FPS_BLOCKS) * 4 + (threadIdx.x >> 6);
    const int lane = threadIdx.x & 63;
    const int b    = wv / NPOINT;
    const int qi   = wv % NPOINT;
    const float* C = pts + (size_t)b * NPTS * 3;

    int widx = 0;
    if (qi > 0) {
      u64* row = slots + (size_t)qi * (BATCH * FPS_SUBS) + b * FPS_SUBS;
      int j = lane & 31;
      u64 v;
      for (;;) {
        v = __hip_atomic_load(&row[j], __ATOMIC_RELAXED,
                              __HIP_MEMORY_SCOPE_AGENT);
        bool ok = ((v >> 63) == 0) &&
                  ((((unsigned)(v >> 20)) & 0x3FFu) == (unsigned)qi);
        if (__all(ok)) break;
        __builtin_amdgcn_s_sleep(64);
      }
      float fv = __uint_as_float((unsigned)(v >> 32));
      int   fi = (int)((unsigned)v & 0xFFFFFu);
#pragma unroll
      for (int off = 32; off >= 1; off >>= 1) {
        float ofv = __shfl_down(fv, off);
        int   ofi = __shfl_down(fi, off);
        if (ofv > fv || (ofv == fv && ofi < fi)) { fv = ofv; fi = ofi; }
      }
      widx = __shfl(fi, 0);
    }

    // q coords: bit-identical to ws_query (fps writes exactly P[widx])
    const float qx = C[widx * 3 + 0];
    const float qy = C[widx * 3 + 1];
    const float qz = C[widx * 3 + 2];
    const float qq = (qx * qx + qy * qy) + qz * qz;

    u64 best[KSEL];
#pragma unroll
    for (int j = 0; j < KSEL; ++j) best[j] = 0xFFFFFFFFFFFFFFFFull;

    for (int j = lane; j < NPTS; j += 64) {
      float px = C[j * 3 + 0], py = C[j * 3 + 1], pz = C[j * 3 + 2];
      float pp  = (px * px + py * py) + pz * pz;
      float dot = __builtin_fmaf(qz, pz, __builtin_fmaf(qy, py, qx * px));
      float d = (qq + pp) - 2.0f * dot;
      d = fmaxf(d, 0.0f);
      u64 key = ((u64)__float_as_uint(d) << 32) | (unsigned)j;
      if (key < best[KSEL - 1]) {
        u64 c = key;
#pragma unroll
        for (int s = 0; s < KSEL; ++s) {
          u64 o = best[s];
          bool l = c < o;
          u64 nb = l ? c : o;
          c = l ? o : c;
          best[s] = nb;
        }
      }
    }

    // LDS-free 64-way merge: repeated wave-min over per-lane heads
    int hp = 1;
    u64 head = best[0];
    int myK = -1, myIdx = 0;
#pragma unroll
    for (int r = 0; r < KSEL; ++r) {
      u64 v = head; int src = lane;
#pragma unroll
      for (int off = 32; off >= 1; off >>= 1) {
        u64 ov = __shfl_down(v, off);
        int os = __shfl_down(src, off);
        if (ov < v) { v = ov; src = os; }  // keys unique (idx embedded)
      }
      v   = __shfl(v, 0);
      src = __shfl(src, 0);
      if (r >= 1 && lane == r - 1) {       // drop r==0 (self)
        myIdx = (int)(unsigned)(v & 0xFFFFFFFFull);
        myK = r - 1;
      }
      if (lane == src) {
        u64 h = 0xFFFFFFFFFFFFFFFFull;
#pragma unroll
        for (int s = 1; s < KSEL; ++s) if (hp == s) h = best[s];
        head = h;
        hp++;
      }
    }

    if (myK >= 0) {
      size_t o = (size_t)(b * NPOINT + qi) * KNN + myK;
      out_nbr_mid[o] = (float)myIdx;
      float sx = C[myIdx * 3 + 0], sy = C[myIdx * 3 + 1],
            sz = C[myIdx * 3 + 2];
      out_d_mid[o * 3 + 0] = qx - sx;
      out_d_mid[o * 3 + 1] = qy - sy;
      out_d_mid[o * 3 + 2] = qz - sz;
    }
  }
}

// ---------------------------------------------------------------------------
// knn_out: unchanged validated kernel (candidates = the 1024 queries).
// Kernel boundary guarantees ws_query visibility.
// ---------------------------------------------------------------------------
#define KNN_WAVES 4

__global__ __launch_bounds__(256)
void knn_kernel(const float* __restrict__ cand_base,
                const float* __restrict__ query_base,
                int ncand,
                float* __restrict__ out_nbr,
                float* __restrict__ out_d) {
#pragma clang fp contract(off)
  const int wid_in_blk = threadIdx.x >> 6;
  const int w    = blockIdx.x * KNN_WAVES + wid_in_blk;
  const int lane = threadIdx.x & 63;
  const int b    = w / NPOINT;
  const int qi   = w % NPOINT;

  const float* C = cand_base + (size_t)b * ncand * 3;
  const float* Q = query_base + ((size_t)b * NPOINT + qi) * 3;
  const float qx = Q[0], qy = Q[1], qz = Q[2];
  const float qq = (qx * qx + qy * qy) + qz * qz;

  u64 best[KSEL];
#pragma unroll
  for (int j = 0; j < KSEL; ++j) best[j] = 0xFFFFFFFFFFFFFFFFull;

  for (int j = lane; j < ncand; j += 64) {
    float px = C[j * 3 + 0], py = C[j * 3 + 1], pz = C[j * 3 + 2];
    float pp  = (px * px + py * py) + pz * pz;
    float dot = __builtin_fmaf(qz, pz, __builtin_fmaf(qy, py, qx * px));
    float d = (qq + pp) - 2.0f * dot;
    d = fmaxf(d, 0.0f);
    u64 key = ((u64)__float_as_uint(d) << 32) | (unsigned)j;
    if (key < best[KSEL - 1]) {
      u64 c = key;
#pragma unroll
      for (int s = 0; s < KSEL; ++s) {
        u64 o = best[s];
        bool l = c < o;
        u64 nb = l ? c : o;
        c = l ? o : c;
        best[s] = nb;
      }
    }
  }

  __shared__ u64 s_list[KNN_WAVES][64 * KSEL];
  u64* L = s_list[wid_in_blk];
#pragma unroll
  for (int j = 0; j < KSEL; ++j) L[lane * KSEL + j] = best[j];
  __syncthreads();

  int hp = 0;
  int myK = -1, myIdx = 0;
  for (int r = 0; r < KSEL; ++r) {
    u64 v = L[lane * KSEL + hp];
    int src = lane;
#pragma unroll
    for (int off = 32; off >= 1; off >>= 1) {
      u64 ov = __shfl_down(v, off);
      int os = __shfl_down(src, off);
      if (ov < v) { v = ov; src = os; }
    }
    v   = __shfl(v, 0);
    src = __shfl(src, 0);
    if (lane == src) hp++;
    if (r >= 1 && lane == r - 1) {
      myIdx = (int)(unsigned)(v & 0xFFFFFFFFull);
      myK = r - 1;
    }
  }

  if (myK >= 0) {
    size_t o = (size_t)(b * NPOINT + qi) * KNN + myK;
    out_nbr[o] = (float)myIdx;
    float sx = C[myIdx * 3 + 0], sy = C[myIdx * 3 + 1], sz = C[myIdx * 3 + 2];
    out_d[o * 3 + 0] = qx - sx;
    out_d[o * 3 + 1] = qy - sy;
    out_d[o * 3 + 2] = qz - sz;
  }
}

// ---------------------------------------------------------------------------
extern "C" void kernel_launch(void* const* d_in, const int* in_sizes, int n_in,
                              void* d_out, int out_size, void* d_ws,
                              size_t ws_size, hipStream_t stream) {
  (void)in_sizes; (void)n_in; (void)out_size; (void)ws_size;
  const float* pts = (const float*)d_in[0];
  float* out = (float*)d_out;

  // ws layout: ind (16KB) | query (48KB) | slots (1024 x 128 x 8B = 1MB)
  int*   ws_ind   = (int*)d_ws;
  float* ws_query = (float*)((char*)d_ws + (size_t)BATCH * NPOINT * sizeof(int));
  u64*   slots    = (u64*)((char*)d_ws + 64 * 1024);

  // output layout (floats): [xyz_ind | xyz_query | nbr_mid | d_mid | nbr_out | d_out]
  float* out_nbr_mid = out + (size_t)BATCH * NPOINT * 4;
  float* out_d_mid   = out_nbr_mid + (size_t)BATCH * NPOINT * KNN;
  float* out_nbr_out = out_d_mid + (size_t)BATCH * NPOINT * KNN * 3;
  float* out_d_out   = out_nbr_out + (size_t)BATCH * NPOINT * KNN;

  hipLaunchKernelGGL(fused_kernel, dim3(FPS_BLOCKS + KNN_BLOCKS),
                     dim3(FPS_TPB), 0, stream,
                     pts, out, ws_ind, ws_query, slots,
                     out_nbr_mid, out_d_mid);

  hipLaunchKernelGGL(knn_kernel, dim3(BATCH * NPOINT / KNN_WAVES), dim3(256),
                     0, stream, ws_query, ws_query, NPOINT, out_nbr_out,
                     out_d_out);
}

// Round 16
// 2586.701 us; speedup vs baseline: 1.3621x; 1.3621x over previous
//
#include <hip/hip_runtime.h>
#include <stdint.h>

#define BATCH   4
#define NPTS    16384
#define NPOINT  1024
#define KNN     20
#define KSEL    21   // K+1, includes self

typedef unsigned long long u64;

// ---------------------------------------------------------------------------
// FUSED single-dispatch design (r16):
//   blocks 0..3      : FPS, EXACT r8 codegen (fastest measured: 2311us) —
//                      single 512-thr block per batch, asm-pinned coords,
//                      parity-LDS reduce. Being single-block it needs NO
//                      cross-block protocol; it just publishes each winner
//                      as one tagged u64 to slots[it*4+b] (relaxed, agent).
//   blocks 4..515    : knn_mid, 8 waves/blk, 1 query/wave: poll ONE word,
//                      q = P[widx] (bit-identical to ws_query, r14-validated),
//                      validated scan + LDS-free merge.
//   blocks 516..1027 : knn_out, 8 waves/blk, 1 query/wave: poll the tagged
//                      slot of each candidate position (self-tagged words ->
//                      no publish-order assumption), gather coords from the
//                      read-only pts (no coherence hazard), same validated
//                      math with key=(d, position) incl. exact-0 self drop.
// Slot word: bit63=0, [29:20]=it tag, [13:0]=widx. 0xAA poison (bit63=1) and
// zeroed ws (tag 0 != it>=1) read "unpublished"; values deterministic ->
// graph-replay idempotent. Consumers only poll, producer never waits ->
// deadlock-free under any dispatch/residency order.
// ---------------------------------------------------------------------------
#define FPS_THREADS 512
#define PPT (NPTS / FPS_THREADS)     // 32 points per thread, strided
#define KNN_MID_BLK0 4
#define KNN_OUT_BLK0 (4 + 512)
#define GRID_BLOCKS  (4 + 512 + 512)

__device__ __forceinline__ float opaque_f(float x) {
  __asm__ volatile("" : "+v"(x));
  return x;
}

#define REPEAT32(M) \
  M(0) M(1) M(2) M(3) M(4) M(5) M(6) M(7) \
  M(8) M(9) M(10) M(11) M(12) M(13) M(14) M(15) \
  M(16) M(17) M(18) M(19) M(20) M(21) M(22) M(23) \
  M(24) M(25) M(26) M(27) M(28) M(29) M(30) M(31)

#define FPS_DECL(i) float px##i, py##i, pz##i, md##i;

#define FPS_INIT(i) { \
    int idx = (i) * FPS_THREADS + t; \
    px##i = opaque_f(P[idx * 3 + 0]); \
    py##i = opaque_f(P[idx * 3 + 1]); \
    pz##i = opaque_f(P[idx * 3 + 2]); \
    md##i = 1e10f; }

#define FPS_STEP(i) { \
    float dx = __fsub_rn(px##i, qx); \
    float dy = __fsub_rn(py##i, qy); \
    float dz = __fsub_rn(pz##i, qz); \
    float d  = __fadd_rn(__fadd_rn(__fmul_rn(dx, dx), __fmul_rn(dy, dy)), \
                         __fmul_rn(dz, dz)); \
    float m = fminf(md##i, d); \
    md##i = m; \
    bool g = (m > best); \
    best = g ? m : best; \
    bi   = g ? (i) : bi; }

__global__ __launch_bounds__(FPS_THREADS)
__attribute__((amdgpu_waves_per_eu(2, 2)))
void fused_kernel(const float* __restrict__ pts, float* __restrict__ out,
                  u64* __restrict__ slots,
                  float* __restrict__ out_nbr_mid,
                  float* __restrict__ out_d_mid,
                  float* __restrict__ out_nbr_out,
                  float* __restrict__ out_d_out) {
  if (blockIdx.x < 4) {
    // ================= FPS role: exact r8 body + slot publish =============
    const int b = blockIdx.x;
    const float* P = pts + (size_t)b * NPTS * 3;
    float* out_ind = out;                   // [B,NPOINT] (indices as float)
    float* out_q   = out + BATCH * NPOINT;  // [B,NPOINT,3]
    const int t = threadIdx.x;

    REPEAT32(FPS_DECL)
    REPEAT32(FPS_INIT)

    __shared__ float s_val[2][FPS_THREADS / 64];
    __shared__ int   s_idx[2][FPS_THREADS / 64];

    if (t == 0) {
      out_ind[b * NPOINT] = 0.0f;
      float ax = P[0], ay = P[1], az = P[2];
      size_t o0 = (size_t)(b * NPOINT) * 3;
      out_q[o0 + 0] = ax; out_q[o0 + 1] = ay; out_q[o0 + 2] = az;
    }
    float qx = P[0], qy = P[1], qz = P[2];

    for (int it = 1; it < NPOINT; ++it) {
      const int p = it & 1;
      float best = -1.0f;
      int bi = 0;
      REPEAT32(FPS_STEP)
      int bidx = bi * FPS_THREADS + t;

      // wave argmax reduce, tie -> lower global index
#pragma unroll
      for (int off = 32; off >= 1; off >>= 1) {
        float ov = __shfl_down(best, off);
        int   oi = __shfl_down(bidx, off);
        if (ov > best || (ov == best && oi < bidx)) { best = ov; bidx = oi; }
      }

      if ((t & 63) == 0) { s_val[p][t >> 6] = best; s_idx[p][t >> 6] = bidx; }
      __syncthreads();

      float bv = s_val[p][0];
      int   bx = s_idx[p][0];
#pragma unroll
      for (int w = 1; w < FPS_THREADS / 64; ++w) {
        float v = s_val[p][w];
        int   x = s_idx[p][w];
        if (v > bv || (v == bv && x < bx)) { bv = v; bx = x; }
      }

      qx = P[bx * 3 + 0];
      qy = P[bx * 3 + 1];
      qz = P[bx * 3 + 2];

      if (t == 0) {
        // publish winner for consumers: bit63=0, [29:20]=it, [13:0]=idx
        u64 pv = (u64)(unsigned)(bx | (it << 20));
        __hip_atomic_store(&slots[(size_t)it * BATCH + b], pv,
                           __ATOMIC_RELAXED, __HIP_MEMORY_SCOPE_AGENT);
        out_ind[b * NPOINT + it] = (float)bx;
        size_t o = (size_t)(b * NPOINT + it) * 3;
        out_q[o + 0] = qx; out_q[o + 1] = qy; out_q[o + 2] = qz;
      }
    }
  } else if (blockIdx.x < KNN_OUT_BLK0) {
    // ================= knn_mid role: one wave per query ===================
#pragma clang fp contract(off)
    const int kb   = blockIdx.x - KNN_MID_BLK0;
    const int wid  = kb * 8 + (threadIdx.x >> 6);
    const int lane = threadIdx.x & 63;
    const int b    = wid >> 10;
    const int qi   = wid & (NPOINT - 1);
    const float* C = pts + (size_t)b * NPTS * 3;

    int widx = 0;
    if (qi > 0) {
      const u64* sp = slots + (size_t)qi * BATCH + b;
      u64 v;
      for (;;) {
        v = __hip_atomic_load(sp, __ATOMIC_RELAXED,
                              __HIP_MEMORY_SCOPE_AGENT);
        if ((v >> 63) == 0 &&
            ((((unsigned)(v >> 20)) & 0x3FFu) == (unsigned)qi)) break;
        __builtin_amdgcn_s_sleep(32);
      }
      widx = (int)((unsigned)v & 0x3FFFu);
    }

    // q coords bit-identical to ws_query/out_q (fps writes exactly P[widx])
    const float qx = C[widx * 3 + 0];
    const float qy = C[widx * 3 + 1];
    const float qz = C[widx * 3 + 2];
    const float qq = (qx * qx + qy * qy) + qz * qz;

    u64 best[KSEL];
#pragma unroll
    for (int j = 0; j < KSEL; ++j) best[j] = 0xFFFFFFFFFFFFFFFFull;

    for (int j = lane; j < NPTS; j += 64) {
      float px = C[j * 3 + 0], py = C[j * 3 + 1], pz = C[j * 3 + 2];
      float pp  = (px * px + py * py) + pz * pz;
      float dot = __builtin_fmaf(qz, pz, __builtin_fmaf(qy, py, qx * px));
      float d = (qq + pp) - 2.0f * dot;
      d = fmaxf(d, 0.0f);
      u64 key = ((u64)__float_as_uint(d) << 32) | (unsigned)j;
      if (key < best[KSEL - 1]) {
        u64 c = key;
#pragma unroll
        for (int s = 0; s < KSEL; ++s) {
          u64 o = best[s];
          bool l = c < o;
          u64 nb = l ? c : o;
          c = l ? o : c;
          best[s] = nb;
        }
      }
    }

    // LDS-free 64-way merge (validated r14)
    int hp = 1;
    u64 head = best[0];
    int myK = -1, myIdx = 0;
#pragma unroll
    for (int r = 0; r < KSEL; ++r) {
      u64 v = head; int src = lane;
#pragma unroll
      for (int off = 32; off >= 1; off >>= 1) {
        u64 ov = __shfl_down(v, off);
        int os = __shfl_down(src, off);
        if (ov < v) { v = ov; src = os; }  // keys unique (idx embedded)
      }
      v   = __shfl(v, 0);
      src = __shfl(src, 0);
      if (r >= 1 && lane == r - 1) {       // drop r==0 (self)
        myIdx = (int)(unsigned)(v & 0xFFFFFFFFull);
        myK = r - 1;
      }
      if (lane == src) {
        u64 h = 0xFFFFFFFFFFFFFFFFull;
#pragma unroll
        for (int s = 1; s < KSEL; ++s) if (hp == s) h = best[s];
        head = h;
        hp++;
      }
    }

    if (myK >= 0) {
      size_t o = (size_t)(b * NPOINT + qi) * KNN + myK;
      out_nbr_mid[o] = (float)myIdx;
      float sx = C[myIdx * 3 + 0], sy = C[myIdx * 3 + 1],
            sz = C[myIdx * 3 + 2];
      out_d_mid[o * 3 + 0] = qx - sx;
      out_d_mid[o * 3 + 1] = qy - sy;
      out_d_mid[o * 3 + 2] = qz - sz;
    }
  } else {
    // ================= knn_out role: one wave per query ===================
#pragma clang fp contract(off)
    const int kb   = blockIdx.x - KNN_OUT_BLK0;
    const int wid  = kb * 8 + (threadIdx.x >> 6);
    const int lane = threadIdx.x & 63;
    const int b    = wid >> 10;
    const int qi   = wid & (NPOINT - 1);
    const float* C = pts + (size_t)b * NPTS * 3;

    // my query's point index
    int wq = 0;
    if (qi > 0) {
      const u64* sp = slots + (size_t)qi * BATCH + b;
      u64 v;
      for (;;) {
        v = __hip_atomic_load(sp, __ATOMIC_RELAXED,
                              __HIP_MEMORY_SCOPE_AGENT);
        if ((v >> 63) == 0 &&
            ((((unsigned)(v >> 20)) & 0x3FFu) == (unsigned)qi)) break;
        __builtin_amdgcn_s_sleep(32);
      }
      wq = (int)((unsigned)v & 0x3FFFu);
    }
    const float qx = C[wq * 3 + 0];
    const float qy = C[wq * 3 + 1];
    const float qz = C[wq * 3 + 2];
    const float qq = (qx * qx + qy * qy) + qz * qz;

    // candidate point indices for my 16 positions (self-tagged words:
    // no publish-order assumption needed)
    int wj[NPOINT / 64];
#pragma unroll
    for (int u = 0; u < NPOINT / 64; ++u) {
      int j = u * 64 + lane;
      int w = 0;
      if (j > 0) {
        const u64* sp = slots + (size_t)j * BATCH + b;
        u64 v;
        for (;;) {
          v = __hip_atomic_load(sp, __ATOMIC_RELAXED,
                                __HIP_MEMORY_SCOPE_AGENT);
          if ((v >> 63) == 0 &&
              ((((unsigned)(v >> 20)) & 0x3FFu) == (unsigned)j)) break;
          __builtin_amdgcn_s_sleep(32);
        }
        w = (int)((unsigned)v & 0x3FFFu);
      }
      wj[u] = w;
    }

    u64 best[KSEL];
#pragma unroll
    for (int j = 0; j < KSEL; ++j) best[j] = 0xFFFFFFFFFFFFFFFFull;

#pragma unroll
    for (int u = 0; u < NPOINT / 64; ++u) {
      int j = u * 64 + lane;               // candidate POSITION (the key idx)
      int w = wj[u];
      float px = C[w * 3 + 0], py = C[w * 3 + 1], pz = C[w * 3 + 2];
      float pp  = (px * px + py * py) + pz * pz;
      float dot = __builtin_fmaf(qz, pz, __builtin_fmaf(qy, py, qx * px));
      float d = (qq + pp) - 2.0f * dot;
      d = fmaxf(d, 0.0f);
      u64 key = ((u64)__float_as_uint(d) << 32) | (unsigned)j;
      if (key < best[KSEL - 1]) {
        u64 c = key;
#pragma unroll
        for (int s = 0; s < KSEL; ++s) {
          u64 o = best[s];
          bool l = c < o;
          u64 nb = l ? c : o;
          c = l ? o : c;
          best[s] = nb;
        }
      }
    }

    // LDS-free 64-way merge (validated r14)
    int hp = 1;
    u64 head = best[0];
    int myK = -1, myIdx = 0;
#pragma unroll
    for (int r = 0; r < KSEL; ++r) {
      u64 v = head; int src = lane;
#pragma unroll
      for (int off = 32; off >= 1; off >>= 1) {
        u64 ov = __shfl_down(v, off);
        int os = __shfl_down(src, off);
        if (ov < v) { v = ov; src = os; }
      }
      v   = __shfl(v, 0);
      src = __shfl(src, 0);
      if (r >= 1 && lane == r - 1) {
        myIdx = (int)(unsigned)(v & 0xFFFFFFFFull);
        myK = r - 1;
      }
      if (lane == src) {
        u64 h = 0xFFFFFFFFFFFFFFFFull;
#pragma unroll
        for (int s = 1; s < KSEL; ++s) if (hp == s) h = best[s];
        head = h;
        hp++;
      }
    }

    if (myK >= 0) {
      // myIdx is a POSITION in the downsampled set; src coords = P[wj[pos]]
      int u = myIdx >> 6, l = myIdx & 63;
      (void)u; (void)l;
      size_t o = (size_t)(b * NPOINT + qi) * KNN + myK;
      out_nbr_out[o] = (float)myIdx;
      // gather the winning candidate's point index again (cheap re-poll —
      // already published, single load)
      int w = 0;
      if (myIdx > 0) {
        u64 v = __hip_atomic_load(slots + (size_t)myIdx * BATCH + b,
                                  __ATOMIC_RELAXED, __HIP_MEMORY_SCOPE_AGENT);
        w = (int)((unsigned)v & 0x3FFFu);
      }
      float sx = C[w * 3 + 0], sy = C[w * 3 + 1], sz = C[w * 3 + 2];
      out_d_out[o * 3 + 0] = qx - sx;
      out_d_out[o * 3 + 1] = qy - sy;
      out_d_out[o * 3 + 2] = qz - sz;
    }
  }
}

// ---------------------------------------------------------------------------
extern "C" void kernel_launch(void* const* d_in, const int* in_sizes, int n_in,
                              void* d_out, int out_size, void* d_ws,
                              size_t ws_size, hipStream_t stream) {
  (void)in_sizes; (void)n_in; (void)out_size; (void)ws_size;
  const float* pts = (const float*)d_in[0];
  float* out = (float*)d_out;

  // ws layout: slots only — 1024 x 4 x 8B = 32 KB
  u64* slots = (u64*)d_ws;

  // output layout (floats): [xyz_ind | xyz_query | nbr_mid | d_mid | nbr_out | d_out]
  float* out_nbr_mid = out + (size_t)BATCH * NPOINT * 4;
  float* out_d_mid   = out_nbr_mid + (size_t)BATCH * NPOINT * KNN;
  float* out_nbr_out = out_d_mid + (size_t)BATCH * NPOINT * KNN * 3;
  float* out_d_out   = out_nbr_out + (size_t)BATCH * NPOINT * KNN;

  hipLaunchKernelGGL(fused_kernel, dim3(GRID_BLOCKS), dim3(FPS_THREADS), 0,
                     stream, pts, out, slots,
                     out_nbr_mid, out_d_mid, out_nbr_out, out_d_out);
}